// Round 1
// baseline (492.888 us; speedup 1.0000x reference)
//
#include <hip/hip_runtime.h>
#include <stdint.h>

// ---------- types ----------
typedef __bf16 bf16_8 __attribute__((ext_vector_type(8)));
typedef __bf16 bf16_4 __attribute__((ext_vector_type(4)));
typedef float  f32x4  __attribute__((ext_vector_type(4)));

#define B_  1
#define S_  2048
#define D_  4096
#define H_  32
#define KV_ 8
#define HD_ 128

__device__ inline void gload_lds16(const void* g, void* l) {
  __builtin_amdgcn_global_load_lds((const __attribute__((address_space(1))) void*)g,
                                   (__attribute__((address_space(3))) void*)l, 16, 0, 0);
}

// ---------- fp32 -> bf16 convert ----------
__global__ __launch_bounds__(256) void cvt_f32_bf16(const float* __restrict__ in,
                                                    __bf16* __restrict__ out, int n4) {
  int i = blockIdx.x * 256 + threadIdx.x;
  if (i >= n4) return;
  float4 v = ((const float4*)in)[i];
  bf16_4 o = { (__bf16)v.x, (__bf16)v.y, (__bf16)v.z, (__bf16)v.w };
  ((bf16_4*)out)[i] = o;
}

// ---------- RoPE (in-place on bf16 Q and K) ----------
__global__ __launch_bounds__(256) void rope_k(__bf16* __restrict__ Qb, __bf16* __restrict__ Kb,
                                              const float* __restrict__ cosT,
                                              const float* __restrict__ sinT) {
  int t = blockIdx.x * 256 + threadIdx.x;
  const int NQ = S_ * (D_ / 8);  // 1,048,576 chunks of 8 for Q
  __bf16* p;
  int row, cl8;
  if (t < NQ) { row = t >> 9; cl8 = t & 511; p = Qb + (size_t)row * D_ + cl8 * 8; }
  else        { int u = t - NQ; row = u >> 7; cl8 = u & 127; p = Kb + (size_t)row * 1024 + cl8 * 8; }
  bf16_8 v = *(bf16_8*)p;
  int fi0 = ((cl8 * 8) & 127) >> 1;  // multiple of 4
  float4 c4 = *(const float4*)&cosT[row * 64 + fi0];
  float4 s4 = *(const float4*)&sinT[row * 64 + fi0];
  float cc[4] = {c4.x, c4.y, c4.z, c4.w};
  float ss[4] = {s4.x, s4.y, s4.z, s4.w};
  bf16_8 o;
#pragma unroll
  for (int j = 0; j < 4; ++j) {
    float xr = (float)v[2 * j], xi = (float)v[2 * j + 1];
    o[2 * j]     = (__bf16)(xr * cc[j] - xi * ss[j]);
    o[2 * j + 1] = (__bf16)(xr * ss[j] + xi * cc[j]);
  }
  *(bf16_8*)p = o;
}

// ---------- fused QKV GEMM (m97-style 128x128 tile, BK=32) ----------
// C[m,n] = sum_k x[m,k] * W[n,k].  Grid: x = 48 col-blocks (32 Q, 8 K, 8 V), y = 16 row-blocks.
__global__ __launch_bounds__(256) void gemm_qkv(const __bf16* __restrict__ xb,
                                                const __bf16* __restrict__ wqb,
                                                const __bf16* __restrict__ wkb,
                                                const __bf16* __restrict__ wvb,
                                                __bf16* __restrict__ Qb,
                                                __bf16* __restrict__ Kb,
                                                __bf16* __restrict__ Vt) {
  __shared__ __bf16 As[128 * 32];
  __shared__ __bf16 Bs[128 * 32];
  const int nb = blockIdx.x, mb = blockIdx.y;
  const __bf16* W; int wrow0;
  if (nb < 32)      { W = wqb; wrow0 = nb * 128; }
  else if (nb < 40) { W = wkb; wrow0 = (nb - 32) * 128; }
  else              { W = wvb; wrow0 = (nb - 40) * 128; }
  const int tid = threadIdx.x, lane = tid & 63, wv = tid >> 6;
  const int wm = wv >> 1, wn = wv & 1;
  const int srow = lane >> 2, scol = (lane & 3) * 8;

  const __bf16* Ag0 = xb + (size_t)(mb * 128 + 2 * wv * 16 + srow) * D_ + scol;
  const __bf16* Bg0 = W  + (size_t)(wrow0 + 2 * wv * 16 + srow) * D_ + scol;
  __bf16* Al = As + 2 * wv * 512;
  __bf16* Bl = Bs + 2 * wv * 512;

  const f32x4 zv = {0.f, 0.f, 0.f, 0.f};
  f32x4 acc[4][4];
#pragma unroll
  for (int i = 0; i < 4; ++i)
#pragma unroll
    for (int j = 0; j < 4; ++j) acc[i][j] = zv;

  for (int k0 = 0; k0 < D_; k0 += 32) {
    gload_lds16(Ag0 + k0, Al);
    gload_lds16(Ag0 + (size_t)16 * D_ + k0, Al + 512);
    gload_lds16(Bg0 + k0, Bl);
    gload_lds16(Bg0 + (size_t)16 * D_ + k0, Bl + 512);
    __syncthreads();
    bf16_8 af[4], bfr[4];
#pragma unroll
    for (int i = 0; i < 4; ++i)
      af[i] = *(const bf16_8*)&As[(wm * 64 + i * 16 + (lane & 15)) * 32 + (lane >> 4) * 8];
#pragma unroll
    for (int j = 0; j < 4; ++j)
      bfr[j] = *(const bf16_8*)&Bs[(wn * 64 + j * 16 + (lane & 15)) * 32 + (lane >> 4) * 8];
#pragma unroll
    for (int i = 0; i < 4; ++i)
#pragma unroll
      for (int j = 0; j < 4; ++j)
        acc[i][j] = __builtin_amdgcn_mfma_f32_16x16x32_bf16(af[i], bfr[j], acc[i][j], 0, 0, 0);
    __syncthreads();
  }

  // epilogue
#pragma unroll
  for (int i = 0; i < 4; ++i) {
    int row0 = mb * 128 + wm * 64 + i * 16 + (lane >> 4) * 4;
#pragma unroll
    for (int j = 0; j < 4; ++j) {
      int cl = wn * 64 + j * 16 + (lane & 15);
      if (nb < 32) {
        int colg = nb * 128 + cl;
#pragma unroll
        for (int r = 0; r < 4; ++r)
          Qb[(size_t)(row0 + r) * D_ + colg] = (__bf16)acc[i][j][r];
      } else if (nb < 40) {
        int colg = (nb - 32) * 128 + cl;
#pragma unroll
        for (int r = 0; r < 4; ++r)
          Kb[(size_t)(row0 + r) * 1024 + colg] = (__bf16)acc[i][j][r];
      } else {
        int colg = (nb - 40) * 128 + cl;
        bf16_4 pv = { (__bf16)acc[i][j][0], (__bf16)acc[i][j][1],
                      (__bf16)acc[i][j][2], (__bf16)acc[i][j][3] };
        *(bf16_4*)&Vt[(size_t)colg * S_ + row0] = pv;  // transposed store
      }
    }
  }
}

// ---------- output-projection GEMM: out(fp32) = Ob @ wo^T ----------
__global__ __launch_bounds__(256) void gemm_out(const __bf16* __restrict__ Ob,
                                                const __bf16* __restrict__ wob,
                                                float* __restrict__ Of) {
  __shared__ __bf16 As[128 * 32];
  __shared__ __bf16 Bs[128 * 32];
  const int nb = blockIdx.x, mb = blockIdx.y;
  const int tid = threadIdx.x, lane = tid & 63, wv = tid >> 6;
  const int wm = wv >> 1, wn = wv & 1;
  const int srow = lane >> 2, scol = (lane & 3) * 8;

  const __bf16* Ag0 = Ob  + (size_t)(mb * 128 + 2 * wv * 16 + srow) * D_ + scol;
  const __bf16* Bg0 = wob + (size_t)(nb * 128 + 2 * wv * 16 + srow) * D_ + scol;
  __bf16* Al = As + 2 * wv * 512;
  __bf16* Bl = Bs + 2 * wv * 512;

  const f32x4 zv = {0.f, 0.f, 0.f, 0.f};
  f32x4 acc[4][4];
#pragma unroll
  for (int i = 0; i < 4; ++i)
#pragma unroll
    for (int j = 0; j < 4; ++j) acc[i][j] = zv;

  for (int k0 = 0; k0 < D_; k0 += 32) {
    gload_lds16(Ag0 + k0, Al);
    gload_lds16(Ag0 + (size_t)16 * D_ + k0, Al + 512);
    gload_lds16(Bg0 + k0, Bl);
    gload_lds16(Bg0 + (size_t)16 * D_ + k0, Bl + 512);
    __syncthreads();
    bf16_8 af[4], bfr[4];
#pragma unroll
    for (int i = 0; i < 4; ++i)
      af[i] = *(const bf16_8*)&As[(wm * 64 + i * 16 + (lane & 15)) * 32 + (lane >> 4) * 8];
#pragma unroll
    for (int j = 0; j < 4; ++j)
      bfr[j] = *(const bf16_8*)&Bs[(wn * 64 + j * 16 + (lane & 15)) * 32 + (lane >> 4) * 8];
#pragma unroll
    for (int i = 0; i < 4; ++i)
#pragma unroll
      for (int j = 0; j < 4; ++j)
        acc[i][j] = __builtin_amdgcn_mfma_f32_16x16x32_bf16(af[i], bfr[j], acc[i][j], 0, 0, 0);
    __syncthreads();
  }

#pragma unroll
  for (int i = 0; i < 4; ++i) {
    int row0 = mb * 128 + wm * 64 + i * 16 + (lane >> 4) * 4;
#pragma unroll
    for (int j = 0; j < 4; ++j) {
      int colg = nb * 128 + wn * 64 + j * 16 + (lane & 15);
#pragma unroll
      for (int r = 0; r < 4; ++r)
        Of[(size_t)(row0 + r) * D_ + colg] = acc[i][j][r];
    }
  }
}

// ---------- flash attention (causal, GQA) ----------
// grid: x = 32 q-blocks (64 rows), y = 32 heads. 256 threads = 4 waves x 16 q-rows.
__global__ __launch_bounds__(256) void attn_k(const __bf16* __restrict__ Qb,
                                              const __bf16* __restrict__ Kb,
                                              const __bf16* __restrict__ Vt,
                                              __bf16* __restrict__ Ob) {
  __shared__ __bf16 Qs[64 * 128];  // swizzled, row stride 256B
  __shared__ __bf16 Ks[64 * 128];
  __shared__ __bf16 Vs[128 * 64];  // Vs[d][k], row stride 128B, swizzled
  __shared__ __bf16 Ps[4][16 * 64];  // per-wave P, row stride 128B, swizzled
  const int qb = blockIdx.x, h = blockIdx.y, kvh = h >> 2;
  const int tid = threadIdx.x, lane = tid & 63, w = tid >> 6;

  // stage Q tile (64 x 128), XOR-swizzled
#pragma unroll
  for (int u = 0; u < 4; ++u) {
    int cid = tid * 4 + u;
    int row = cid >> 4, c8 = cid & 15;
    bf16_8 t = *(const bf16_8*)&Qb[(size_t)(qb * 64 + row) * D_ + h * 128 + c8 * 8];
    int bo = (row * 256 + c8 * 16) ^ ((row & 7) << 4);
    *(bf16_8*)((char*)Qs + bo) = t;
  }
  __syncthreads();

  bf16_8 aq[4];
#pragma unroll
  for (int ks = 0; ks < 4; ++ks) {
    int row = w * 16 + (lane & 15);
    int bo = (row * 256 + (ks * 32 + (lane >> 4) * 8) * 2) ^ ((row & 7) << 4);
    aq[ks] = *(const bf16_8*)((char*)Qs + bo);
  }

  const f32x4 zv = {0.f, 0.f, 0.f, 0.f};
  f32x4 accO[8];
#pragma unroll
  for (int d = 0; d < 8; ++d) accO[d] = zv;
  float mrun[4], lrun[4];
#pragma unroll
  for (int r = 0; r < 4; ++r) { mrun[r] = -3e38f; lrun[r] = 0.f; }

  const float sc = 0.08838834764831845f;  // 1/sqrt(128)
  const int qrow_base = qb * 64 + w * 16 + (lane >> 4) * 4;

  for (int kb = 0; kb <= qb; ++kb) {
    // stage K (64 x 128) and V^T (128 x 64)
#pragma unroll
    for (int u = 0; u < 4; ++u) {
      int cid = tid * 4 + u;
      int row = cid >> 4, c8 = cid & 15;
      bf16_8 t = *(const bf16_8*)&Kb[(size_t)(kb * 64 + row) * 1024 + kvh * 128 + c8 * 8];
      int bo = (row * 256 + c8 * 16) ^ ((row & 7) << 4);
      *(bf16_8*)((char*)Ks + bo) = t;
    }
#pragma unroll
    for (int u = 0; u < 4; ++u) {
      int cid = tid * 4 + u;
      int vr = cid >> 3, c8 = cid & 7;
      bf16_8 t = *(const bf16_8*)&Vt[(size_t)(kvh * 128 + vr) * S_ + kb * 64 + c8 * 8];
      int bo = (vr * 128 + c8 * 16) ^ ((vr & 7) << 4);
      *(bf16_8*)((char*)Vs + bo) = t;
    }
    __syncthreads();

    // S = Q K^T  (16 rows x 64 cols per wave)
    f32x4 sfr[4];
#pragma unroll
    for (int nf = 0; nf < 4; ++nf) {
      f32x4 c = zv;
#pragma unroll
      for (int ks = 0; ks < 4; ++ks) {
        int n = nf * 16 + (lane & 15);
        int bo = (n * 256 + (ks * 32 + (lane >> 4) * 8) * 2) ^ ((n & 7) << 4);
        bf16_8 bk = *(const bf16_8*)((char*)Ks + bo);
        c = __builtin_amdgcn_mfma_f32_16x16x32_bf16(aq[ks], bk, c, 0, 0, 0);
      }
      sfr[nf] = c;
    }

    // scale + causal mask + row max
    float pm[4];
#pragma unroll
    for (int r = 0; r < 4; ++r) pm[r] = -3e38f;
#pragma unroll
    for (int nf = 0; nf < 4; ++nf) {
      int col = kb * 64 + nf * 16 + (lane & 15);
#pragma unroll
      for (int r = 0; r < 4; ++r) {
        float v = sfr[nf][r] * sc;
        if (col > qrow_base + r) v = -1e9f;
        sfr[nf][r] = v;
        pm[r] = fmaxf(pm[r], v);
      }
    }
#pragma unroll
    for (int m = 1; m < 16; m <<= 1) {
#pragma unroll
      for (int r = 0; r < 4; ++r) pm[r] = fmaxf(pm[r], __shfl_xor(pm[r], m));
    }

    float mnew[4], resc[4], psum[4];
#pragma unroll
    for (int r = 0; r < 4; ++r) {
      mnew[r] = fmaxf(mrun[r], pm[r]);
      resc[r] = __expf(mrun[r] - mnew[r]);
      psum[r] = 0.f;
    }

    // P = exp(S - m), write to per-wave LDS (swizzled)
#pragma unroll
    for (int nf = 0; nf < 4; ++nf) {
#pragma unroll
      for (int r = 0; r < 4; ++r) {
        float p = __expf(sfr[nf][r] - mnew[r]);
        psum[r] += p;
        int prow = (lane >> 4) * 4 + r, pcol = nf * 16 + (lane & 15);
        int bo = (prow * 128 + pcol * 2) ^ ((prow & 7) << 4);
        *(__bf16*)((char*)(&Ps[w][0]) + bo) = (__bf16)p;
      }
    }
#pragma unroll
    for (int m = 1; m < 16; m <<= 1) {
#pragma unroll
      for (int r = 0; r < 4; ++r) psum[r] += __shfl_xor(psum[r], m);
    }
#pragma unroll
    for (int r = 0; r < 4; ++r) {
      lrun[r] = lrun[r] * resc[r] + psum[r];
      mrun[r] = mnew[r];
    }
#pragma unroll
    for (int d = 0; d < 8; ++d)
#pragma unroll
      for (int r = 0; r < 4; ++r) accO[d][r] *= resc[r];

    // O += P V
    bf16_8 ap[2];
#pragma unroll
    for (int ks = 0; ks < 2; ++ks) {
      int m_ = lane & 15;
      int bo = (m_ * 128 + (ks * 32 + (lane >> 4) * 8) * 2) ^ ((m_ & 7) << 4);
      ap[ks] = *(const bf16_8*)((char*)(&Ps[w][0]) + bo);
    }
#pragma unroll
    for (int d = 0; d < 8; ++d) {
#pragma unroll
      for (int ks = 0; ks < 2; ++ks) {
        int dr = d * 16 + (lane & 15);
        int bo = (dr * 128 + (ks * 32 + (lane >> 4) * 8) * 2) ^ ((dr & 7) << 4);
        bf16_8 bv = *(const bf16_8*)((char*)Vs + bo);
        accO[d] = __builtin_amdgcn_mfma_f32_16x16x32_bf16(ap[ks], bv, accO[d], 0, 0, 0);
      }
    }
    __syncthreads();
  }

  // normalize + store
  float inv[4];
#pragma unroll
  for (int r = 0; r < 4; ++r) inv[r] = 1.0f / lrun[r];
#pragma unroll
  for (int d = 0; d < 8; ++d) {
#pragma unroll
    for (int r = 0; r < 4; ++r) {
      size_t row = qb * 64 + w * 16 + (lane >> 4) * 4 + r;
      Ob[row * D_ + h * 128 + d * 16 + (lane & 15)] = (__bf16)(accO[d][r] * inv[r]);
    }
  }
}

// ---------- launch ----------
extern "C" void kernel_launch(void* const* d_in, const int* in_sizes, int n_in,
                              void* d_out, int out_size, void* d_ws, size_t ws_size,
                              hipStream_t stream) {
  const float* x    = (const float*)d_in[0];
  const float* wq   = (const float*)d_in[1];
  const float* wk   = (const float*)d_in[2];
  const float* wv   = (const float*)d_in[3];
  const float* wo   = (const float*)d_in[4];
  const float* cosT = (const float*)d_in[5];
  const float* sinT = (const float*)d_in[6];
  // d_in[7] cache (zeros, start_pos=0 -> keys==xk), d_in[8] mask (causal), d_in[9] start_pos: unused
  float* out = (float*)d_out;
  char* ws = (char*)d_ws;

  __bf16* xb  = (__bf16*)(ws + 0);            // 2048x4096 (16.78 MB); later reused as Ob
  __bf16* wqb = (__bf16*)(ws + 16777216);     // 4096x4096
  __bf16* wkb = (__bf16*)(ws + 50331648);     // 1024x4096
  __bf16* wvb = (__bf16*)(ws + 58720256);     // 1024x4096
  __bf16* wob = (__bf16*)(ws + 67108864);     // 4096x4096
  __bf16* Qb  = (__bf16*)(ws + 100663296);    // 2048x4096
  __bf16* Kb  = (__bf16*)(ws + 117440512);    // 2048x1024
  __bf16* Vt  = (__bf16*)(ws + 121634816);    // 1024x2048 (V transposed)
  __bf16* Ob  = xb;                           // alias: x consumed before attention writes

  // fp32 -> bf16
  cvt_f32_bf16<<<(2097152 + 255) / 256, 256, 0, stream>>>(x,  xb,  2097152);
  cvt_f32_bf16<<<(4194304 + 255) / 256, 256, 0, stream>>>(wq, wqb, 4194304);
  cvt_f32_bf16<<<(1048576 + 255) / 256, 256, 0, stream>>>(wk, wkb, 1048576);
  cvt_f32_bf16<<<(1048576 + 255) / 256, 256, 0, stream>>>(wv, wvb, 1048576);
  cvt_f32_bf16<<<(4194304 + 255) / 256, 256, 0, stream>>>(wo, wob, 4194304);

  // fused QKV projection (V stored transposed)
  gemm_qkv<<<dim3(48, 16), 256, 0, stream>>>(xb, wqb, wkb, wvb, Qb, Kb, Vt);

  // RoPE on Q and K (in place)
  rope_k<<<5120, 256, 0, stream>>>(Qb, Kb, cosT, sinT);

  // causal GQA flash attention
  attn_k<<<dim3(32, 32), 256, 0, stream>>>(Qb, Kb, Vt, Ob);

  // output projection -> fp32
  gemm_out<<<dim3(32, 16), 256, 0, stream>>>(Ob, wob, out);
}

// Round 2
// 467.026 us; speedup vs baseline: 1.0554x; 1.0554x over previous
//
#include <hip/hip_runtime.h>
#include <stdint.h>

// ---------- types ----------
typedef __bf16 bf16_8 __attribute__((ext_vector_type(8)));
typedef __bf16 bf16_4 __attribute__((ext_vector_type(4)));
typedef float  f32x4  __attribute__((ext_vector_type(4)));

#define B_  1
#define S_  2048
#define D_  4096
#define H_  32
#define KV_ 8
#define HD_ 128

__device__ inline void gload_lds16(const void* g, void* l) {
  __builtin_amdgcn_global_load_lds((const __attribute__((address_space(1))) void*)g,
                                   (__attribute__((address_space(3))) void*)l, 16, 0, 0);
}

// ---------- fused fp32 -> bf16 convert (all 5 tensors; dst contiguous in ws) ----------
__global__ __launch_bounds__(256) void cvt_all(const float* __restrict__ x,
                                               const float* __restrict__ wq,
                                               const float* __restrict__ wk,
                                               const float* __restrict__ wv,
                                               const float* __restrict__ wo,
                                               __bf16* __restrict__ dst) {
  int i = blockIdx.x * 256 + threadIdx.x;  // float4-chunk index, total 12,582,912
  const float* s;
  int j = i;
  if (j < 2097152) s = x;
  else if ((j -= 2097152) < 4194304) s = wq;
  else if ((j -= 4194304) < 1048576) s = wk;
  else if ((j -= 1048576) < 1048576) s = wv;
  else { j -= 1048576; s = wo; }
  float4 v = ((const float4*)s)[j];
  bf16_4 o = { (__bf16)v.x, (__bf16)v.y, (__bf16)v.z, (__bf16)v.w };
  ((bf16_4*)dst)[i] = o;
}

// ---------- RoPE (in-place on bf16 Q and K) ----------
__global__ __launch_bounds__(256) void rope_k(__bf16* __restrict__ Qb, __bf16* __restrict__ Kb,
                                              const float* __restrict__ cosT,
                                              const float* __restrict__ sinT) {
  int t = blockIdx.x * 256 + threadIdx.x;
  const int NQ = S_ * (D_ / 8);
  __bf16* p;
  int row, cl8;
  if (t < NQ) { row = t >> 9; cl8 = t & 511; p = Qb + (size_t)row * D_ + cl8 * 8; }
  else        { int u = t - NQ; row = u >> 7; cl8 = u & 127; p = Kb + (size_t)row * 1024 + cl8 * 8; }
  bf16_8 v = *(bf16_8*)p;
  int fi0 = ((cl8 * 8) & 127) >> 1;
  float4 c4 = *(const float4*)&cosT[row * 64 + fi0];
  float4 s4 = *(const float4*)&sinT[row * 64 + fi0];
  float cc[4] = {c4.x, c4.y, c4.z, c4.w};
  float ss[4] = {s4.x, s4.y, s4.z, s4.w};
  bf16_8 o;
#pragma unroll
  for (int j = 0; j < 4; ++j) {
    float xr = (float)v[2 * j], xi = (float)v[2 * j + 1];
    o[2 * j]     = (__bf16)(xr * cc[j] - xi * ss[j]);
    o[2 * j + 1] = (__bf16)(xr * ss[j] + xi * cc[j]);
  }
  *(bf16_8*)p = o;
}

// ---------- fused QKV GEMM (m97-style 128x128 tile, BK=32) ----------
__global__ __launch_bounds__(256) void gemm_qkv(const __bf16* __restrict__ xb,
                                                const __bf16* __restrict__ wqb,
                                                const __bf16* __restrict__ wkb,
                                                const __bf16* __restrict__ wvb,
                                                __bf16* __restrict__ Qb,
                                                __bf16* __restrict__ Kb,
                                                __bf16* __restrict__ Vt) {
  __shared__ __bf16 As[128 * 32];
  __shared__ __bf16 Bs[128 * 32];
  const int nb = blockIdx.x, mb = blockIdx.y;
  const __bf16* W; int wrow0;
  if (nb < 32)      { W = wqb; wrow0 = nb * 128; }
  else if (nb < 40) { W = wkb; wrow0 = (nb - 32) * 128; }
  else              { W = wvb; wrow0 = (nb - 40) * 128; }
  const int tid = threadIdx.x, lane = tid & 63, wv = tid >> 6;
  const int wm = wv >> 1, wn = wv & 1;
  const int srow = lane >> 2, scol = (lane & 3) * 8;

  const __bf16* Ag0 = xb + (size_t)(mb * 128 + 2 * wv * 16 + srow) * D_ + scol;
  const __bf16* Bg0 = W  + (size_t)(wrow0 + 2 * wv * 16 + srow) * D_ + scol;
  __bf16* Al = As + 2 * wv * 512;
  __bf16* Bl = Bs + 2 * wv * 512;

  const f32x4 zv = {0.f, 0.f, 0.f, 0.f};
  f32x4 acc[4][4];
#pragma unroll
  for (int i = 0; i < 4; ++i)
#pragma unroll
    for (int j = 0; j < 4; ++j) acc[i][j] = zv;

  for (int k0 = 0; k0 < D_; k0 += 32) {
    gload_lds16(Ag0 + k0, Al);
    gload_lds16(Ag0 + (size_t)16 * D_ + k0, Al + 512);
    gload_lds16(Bg0 + k0, Bl);
    gload_lds16(Bg0 + (size_t)16 * D_ + k0, Bl + 512);
    __syncthreads();
    bf16_8 af[4], bfr[4];
#pragma unroll
    for (int i = 0; i < 4; ++i)
      af[i] = *(const bf16_8*)&As[(wm * 64 + i * 16 + (lane & 15)) * 32 + (lane >> 4) * 8];
#pragma unroll
    for (int j = 0; j < 4; ++j)
      bfr[j] = *(const bf16_8*)&Bs[(wn * 64 + j * 16 + (lane & 15)) * 32 + (lane >> 4) * 8];
#pragma unroll
    for (int i = 0; i < 4; ++i)
#pragma unroll
      for (int j = 0; j < 4; ++j)
        acc[i][j] = __builtin_amdgcn_mfma_f32_16x16x32_bf16(af[i], bfr[j], acc[i][j], 0, 0, 0);
    __syncthreads();
  }

#pragma unroll
  for (int i = 0; i < 4; ++i) {
    int row0 = mb * 128 + wm * 64 + i * 16 + (lane >> 4) * 4;
#pragma unroll
    for (int j = 0; j < 4; ++j) {
      int cl = wn * 64 + j * 16 + (lane & 15);
      if (nb < 32) {
        int colg = nb * 128 + cl;
#pragma unroll
        for (int r = 0; r < 4; ++r)
          Qb[(size_t)(row0 + r) * D_ + colg] = (__bf16)acc[i][j][r];
      } else if (nb < 40) {
        int colg = (nb - 32) * 128 + cl;
#pragma unroll
        for (int r = 0; r < 4; ++r)
          Kb[(size_t)(row0 + r) * 1024 + colg] = (__bf16)acc[i][j][r];
      } else {
        int colg = (nb - 40) * 128 + cl;
        bf16_4 pv = { (__bf16)acc[i][j][0], (__bf16)acc[i][j][1],
                      (__bf16)acc[i][j][2], (__bf16)acc[i][j][3] };
        *(bf16_4*)&Vt[(size_t)colg * S_ + row0] = pv;  // transposed store
      }
    }
  }
}

// ---------- output-projection GEMM: out(fp32) = Ob @ wo^T ----------
__global__ __launch_bounds__(256) void gemm_out(const __bf16* __restrict__ Ob,
                                                const __bf16* __restrict__ wob,
                                                float* __restrict__ Of) {
  __shared__ __bf16 As[128 * 32];
  __shared__ __bf16 Bs[128 * 32];
  const int nb = blockIdx.x, mb = blockIdx.y;
  const int tid = threadIdx.x, lane = tid & 63, wv = tid >> 6;
  const int wm = wv >> 1, wn = wv & 1;
  const int srow = lane >> 2, scol = (lane & 3) * 8;

  const __bf16* Ag0 = Ob  + (size_t)(mb * 128 + 2 * wv * 16 + srow) * D_ + scol;
  const __bf16* Bg0 = wob + (size_t)(nb * 128 + 2 * wv * 16 + srow) * D_ + scol;
  __bf16* Al = As + 2 * wv * 512;
  __bf16* Bl = Bs + 2 * wv * 512;

  const f32x4 zv = {0.f, 0.f, 0.f, 0.f};
  f32x4 acc[4][4];
#pragma unroll
  for (int i = 0; i < 4; ++i)
#pragma unroll
    for (int j = 0; j < 4; ++j) acc[i][j] = zv;

  for (int k0 = 0; k0 < D_; k0 += 32) {
    gload_lds16(Ag0 + k0, Al);
    gload_lds16(Ag0 + (size_t)16 * D_ + k0, Al + 512);
    gload_lds16(Bg0 + k0, Bl);
    gload_lds16(Bg0 + (size_t)16 * D_ + k0, Bl + 512);
    __syncthreads();
    bf16_8 af[4], bfr[4];
#pragma unroll
    for (int i = 0; i < 4; ++i)
      af[i] = *(const bf16_8*)&As[(wm * 64 + i * 16 + (lane & 15)) * 32 + (lane >> 4) * 8];
#pragma unroll
    for (int j = 0; j < 4; ++j)
      bfr[j] = *(const bf16_8*)&Bs[(wn * 64 + j * 16 + (lane & 15)) * 32 + (lane >> 4) * 8];
#pragma unroll
    for (int i = 0; i < 4; ++i)
#pragma unroll
      for (int j = 0; j < 4; ++j)
        acc[i][j] = __builtin_amdgcn_mfma_f32_16x16x32_bf16(af[i], bfr[j], acc[i][j], 0, 0, 0);
    __syncthreads();
  }

#pragma unroll
  for (int i = 0; i < 4; ++i) {
    int row0 = mb * 128 + wm * 64 + i * 16 + (lane >> 4) * 4;
#pragma unroll
    for (int j = 0; j < 4; ++j) {
      int colg = nb * 128 + wn * 64 + j * 16 + (lane & 15);
#pragma unroll
      for (int r = 0; r < 4; ++r)
        Of[(size_t)(row0 + r) * D_ + colg] = acc[i][j][r];
    }
  }
}

// ---------- flash attention (causal, GQA), paired-triangle balance ----------
// grid: x = 16 q-tile PAIRS (qlo=x, qhi=31-x, 64 rows each), y = 32 heads.
// 256 threads = 4 waves x 16 q-rows per tile. One K/V stage feeds both tiles.
// Per-tile softmax/PV math identical to verified R0 kernel.
#define COMPUTE_TILE(ACC, MR, LR, AQ, QB0, DOMASK)                               \
  {                                                                              \
    f32x4 sfr_[4];                                                               \
    _Pragma("unroll")                                                            \
    for (int nf = 0; nf < 4; ++nf) {                                             \
      f32x4 c_ = zv;                                                             \
      _Pragma("unroll")                                                          \
      for (int ks = 0; ks < 4; ++ks) {                                           \
        int n_ = nf * 16 + (lane & 15);                                          \
        int bo_ = (n_ * 256 + (ks * 32 + (lane >> 4) * 8) * 2) ^ ((n_ & 7) << 4);\
        bf16_8 bk_ = *(const bf16_8*)((char*)Ks + bo_);                          \
        c_ = __builtin_amdgcn_mfma_f32_16x16x32_bf16(AQ[ks], bk_, c_, 0, 0, 0);  \
      }                                                                          \
      sfr_[nf] = c_;                                                             \
    }                                                                            \
    float pm_[4] = {-3e38f, -3e38f, -3e38f, -3e38f};                             \
    const int qrb_ = (QB0) + w * 16 + (lane >> 4) * 4;                           \
    _Pragma("unroll")                                                            \
    for (int nf = 0; nf < 4; ++nf) {                                             \
      int col_ = kb * 64 + nf * 16 + (lane & 15);                                \
      _Pragma("unroll")                                                          \
      for (int r = 0; r < 4; ++r) {                                              \
        float v_ = sfr_[nf][r] * sc;                                             \
        if ((DOMASK) && col_ > qrb_ + r) v_ = -1e9f;                             \
        sfr_[nf][r] = v_;                                                        \
        pm_[r] = fmaxf(pm_[r], v_);                                              \
      }                                                                          \
    }                                                                            \
    _Pragma("unroll")                                                            \
    for (int m_ = 1; m_ < 16; m_ <<= 1) {                                        \
      _Pragma("unroll")                                                          \
      for (int r = 0; r < 4; ++r) pm_[r] = fmaxf(pm_[r], __shfl_xor(pm_[r], m_));\
    }                                                                            \
    bool skip_ = __all(pm_[0] <= MR[0] + 8.f && pm_[1] <= MR[1] + 8.f &&         \
                       pm_[2] <= MR[2] + 8.f && pm_[3] <= MR[3] + 8.f);          \
    if (!skip_) {                                                                \
      _Pragma("unroll")                                                          \
      for (int r = 0; r < 4; ++r) {                                              \
        float mn_ = fmaxf(MR[r], pm_[r]);                                        \
        float rs_ = __expf(MR[r] - mn_);                                         \
        MR[r] = mn_;                                                             \
        LR[r] *= rs_;                                                            \
        _Pragma("unroll")                                                        \
        for (int d = 0; d < 8; ++d) ACC[d][r] *= rs_;                            \
      }                                                                          \
    }                                                                            \
    float ps_[4] = {0.f, 0.f, 0.f, 0.f};                                         \
    _Pragma("unroll")                                                            \
    for (int nf = 0; nf < 4; ++nf) {                                             \
      _Pragma("unroll")                                                          \
      for (int r = 0; r < 4; ++r) {                                              \
        float p_ = __expf(sfr_[nf][r] - MR[r]);                                  \
        ps_[r] += p_;                                                            \
        int pr_ = (lane >> 4) * 4 + r, pc_ = nf * 16 + (lane & 15);              \
        int bo_ = (pr_ * 128 + pc_ * 2) ^ ((pr_ & 7) << 4);                      \
        *(__bf16*)((char*)(&Ps[w][0]) + bo_) = (__bf16)p_;                       \
      }                                                                          \
    }                                                                            \
    _Pragma("unroll")                                                            \
    for (int m_ = 1; m_ < 16; m_ <<= 1) {                                        \
      _Pragma("unroll")                                                          \
      for (int r = 0; r < 4; ++r) ps_[r] += __shfl_xor(ps_[r], m_);              \
    }                                                                            \
    _Pragma("unroll")                                                            \
    for (int r = 0; r < 4; ++r) LR[r] += ps_[r];                                 \
    bf16_8 ap_[2];                                                               \
    _Pragma("unroll")                                                            \
    for (int ks = 0; ks < 2; ++ks) {                                             \
      int mm_ = lane & 15;                                                       \
      int bo_ = (mm_ * 128 + (ks * 32 + (lane >> 4) * 8) * 2) ^ ((mm_ & 7) << 4);\
      ap_[ks] = *(const bf16_8*)((char*)(&Ps[w][0]) + bo_);                      \
    }                                                                            \
    _Pragma("unroll")                                                            \
    for (int d = 0; d < 8; ++d) {                                                \
      _Pragma("unroll")                                                          \
      for (int ks = 0; ks < 2; ++ks) {                                           \
        int dr_ = d * 16 + (lane & 15);                                          \
        int bo_ = (dr_ * 128 + (ks * 32 + (lane >> 4) * 8) * 2) ^ ((dr_ & 7) << 4);\
        bf16_8 bv_ = *(const bf16_8*)((char*)Vs + bo_);                          \
        ACC[d] = __builtin_amdgcn_mfma_f32_16x16x32_bf16(ap_[ks], bv_, ACC[d], 0, 0, 0); \
      }                                                                          \
    }                                                                            \
  }

__global__ __launch_bounds__(256) void attn_k(const __bf16* __restrict__ Qb,
                                              const __bf16* __restrict__ Kb,
                                              const __bf16* __restrict__ Vt,
                                              __bf16* __restrict__ Ob) {
  __shared__ __bf16 Ks[64 * 128];    // swizzled, row stride 256B
  __shared__ __bf16 Vs[128 * 64];    // Vs[d][k], row stride 128B, swizzled
  __shared__ __bf16 Ps[4][16 * 64];  // per-wave P, row stride 128B, swizzled
  const int x = blockIdx.x, h = blockIdx.y, kvh = h >> 2;
  const int qlo = x, qhi = 31 - x;
  const int tid = threadIdx.x, lane = tid & 63, w = tid >> 6;

  // Q fragments straight from global (once per block, both tiles)
  bf16_8 aq0[4], aq1[4];
#pragma unroll
  for (int ks = 0; ks < 4; ++ks) {
    int rr = w * 16 + (lane & 15);
    int cc = h * 128 + ks * 32 + (lane >> 4) * 8;
    aq0[ks] = *(const bf16_8*)&Qb[(size_t)(qlo * 64 + rr) * D_ + cc];
    aq1[ks] = *(const bf16_8*)&Qb[(size_t)(qhi * 64 + rr) * D_ + cc];
  }

  const f32x4 zv = {0.f, 0.f, 0.f, 0.f};
  f32x4 accO0[8], accO1[8];
#pragma unroll
  for (int d = 0; d < 8; ++d) { accO0[d] = zv; accO1[d] = zv; }
  float mr0[4], lr0[4], mr1[4], lr1[4];
#pragma unroll
  for (int r = 0; r < 4; ++r) { mr0[r] = mr1[r] = -3e38f; lr0[r] = lr1[r] = 0.f; }

  const float sc = 0.08838834764831845f;  // 1/sqrt(128)

  // staging registers (async-split: load early, LDS-write after barrier)
  bf16_8 rK[4], rV[4];
#define KLOAD(KB)                                                                 \
  {                                                                               \
    _Pragma("unroll")                                                             \
    for (int u = 0; u < 4; ++u) {                                                 \
      int cid = tid * 4 + u; int row = cid >> 4, c8 = cid & 15;                   \
      rK[u] = *(const bf16_8*)&Kb[(size_t)((KB) * 64 + row) * 1024 + kvh * 128 + c8 * 8]; \
    }                                                                             \
    _Pragma("unroll")                                                             \
    for (int u = 0; u < 4; ++u) {                                                 \
      int cid = tid * 4 + u; int vr = cid >> 3, c8 = cid & 7;                     \
      rV[u] = *(const bf16_8*)&Vt[(size_t)(kvh * 128 + vr) * S_ + (KB) * 64 + c8 * 8]; \
    }                                                                             \
  }
#define KSTORE()                                                                  \
  {                                                                               \
    _Pragma("unroll")                                                             \
    for (int u = 0; u < 4; ++u) {                                                 \
      int cid = tid * 4 + u; int row = cid >> 4, c8 = cid & 15;                   \
      int bo = (row * 256 + c8 * 16) ^ ((row & 7) << 4);                          \
      *(bf16_8*)((char*)Ks + bo) = rK[u];                                         \
    }                                                                             \
    _Pragma("unroll")                                                             \
    for (int u = 0; u < 4; ++u) {                                                 \
      int cid = tid * 4 + u; int vr = cid >> 3, c8 = cid & 7;                     \
      int bo = (vr * 128 + c8 * 16) ^ ((vr & 7) << 4);                            \
      *(bf16_8*)((char*)Vs + bo) = rV[u];                                         \
    }                                                                             \
  }

  KLOAD(0);
  KSTORE();
  __syncthreads();

  for (int kb = 0; kb <= qhi; ++kb) {
    if (kb < qhi) KLOAD(kb + 1);  // in flight during compute
    COMPUTE_TILE(accO1, mr1, lr1, aq1, qhi * 64, (kb == qhi));
    if (kb <= qlo) COMPUTE_TILE(accO0, mr0, lr0, aq0, qlo * 64, (kb == qlo));
    if (kb < qhi) {
      __syncthreads();  // everyone done reading Ks/Vs
      KSTORE();         // waits vmcnt for rK/rV automatically
      __syncthreads();  // tile kb+1 ready
    }
  }

  // normalize + store both tiles
  float inv0[4], inv1[4];
#pragma unroll
  for (int r = 0; r < 4; ++r) { inv0[r] = 1.0f / lr0[r]; inv1[r] = 1.0f / lr1[r]; }
#pragma unroll
  for (int d = 0; d < 8; ++d) {
#pragma unroll
    for (int r = 0; r < 4; ++r) {
      size_t rl = (size_t)(qlo * 64 + w * 16 + (lane >> 4) * 4 + r);
      size_t rh = (size_t)(qhi * 64 + w * 16 + (lane >> 4) * 4 + r);
      int cc = h * 128 + d * 16 + (lane & 15);
      Ob[rl * D_ + cc] = (__bf16)(accO0[d][r] * inv0[r]);
      Ob[rh * D_ + cc] = (__bf16)(accO1[d][r] * inv1[r]);
    }
  }
}

// ---------- launch ----------
extern "C" void kernel_launch(void* const* d_in, const int* in_sizes, int n_in,
                              void* d_out, int out_size, void* d_ws, size_t ws_size,
                              hipStream_t stream) {
  const float* x    = (const float*)d_in[0];
  const float* wq   = (const float*)d_in[1];
  const float* wk   = (const float*)d_in[2];
  const float* wv   = (const float*)d_in[3];
  const float* wo   = (const float*)d_in[4];
  const float* cosT = (const float*)d_in[5];
  const float* sinT = (const float*)d_in[6];
  float* out = (float*)d_out;
  char* ws = (char*)d_ws;

  __bf16* xb  = (__bf16*)(ws + 0);            // 2048x4096; later reused as Ob
  __bf16* wqb = (__bf16*)(ws + 16777216);     // 4096x4096
  __bf16* wkb = (__bf16*)(ws + 50331648);     // 1024x4096
  __bf16* wvb = (__bf16*)(ws + 58720256);     // 1024x4096
  __bf16* wob = (__bf16*)(ws + 67108864);     // 4096x4096
  __bf16* Qb  = (__bf16*)(ws + 100663296);    // 2048x4096
  __bf16* Kb  = (__bf16*)(ws + 117440512);    // 2048x1024
  __bf16* Vt  = (__bf16*)(ws + 121634816);    // 1024x2048 (V transposed)
  __bf16* Ob  = xb;                           // alias: x consumed before attention writes

  // fused fp32 -> bf16 (dst = xb..wob contiguous)
  cvt_all<<<49152, 256, 0, stream>>>(x, wq, wk, wv, wo, xb);

  // fused QKV projection (V stored transposed)
  gemm_qkv<<<dim3(48, 16), 256, 0, stream>>>(xb, wqb, wkb, wvb, Qb, Kb, Vt);

  // RoPE on Q and K (in place)
  rope_k<<<5120, 256, 0, stream>>>(Qb, Kb, cosT, sinT);

  // causal GQA flash attention (paired triangle)
  attn_k<<<dim3(16, 32), 256, 0, stream>>>(Qb, Kb, Vt, Ob);

  // output projection -> fp32
  gemm_out<<<dim3(32, 16), 256, 0, stream>>>(Ob, wob, out);
}

// Round 3
// 395.454 us; speedup vs baseline: 1.2464x; 1.1810x over previous
//
#include <hip/hip_runtime.h>
#include <stdint.h>

// ---------- types ----------
typedef __bf16 bf16_8 __attribute__((ext_vector_type(8)));
typedef __bf16 bf16_4 __attribute__((ext_vector_type(4)));
typedef float  f32x4  __attribute__((ext_vector_type(4)));

#define B_  1
#define S_  2048
#define D_  4096
#define H_  32
#define KV_ 8
#define HD_ 128

__device__ inline void gload_lds16(const void* g, void* l) {
  __builtin_amdgcn_global_load_lds((const __attribute__((address_space(1))) void*)g,
                                   (__attribute__((address_space(3))) void*)l, 16, 0, 0);
}

// ---------- fused fp32 -> bf16 convert (all 5 tensors; dst contiguous in ws) ----------
__global__ __launch_bounds__(256) void cvt_all(const float* __restrict__ x,
                                               const float* __restrict__ wq,
                                               const float* __restrict__ wk,
                                               const float* __restrict__ wv,
                                               const float* __restrict__ wo,
                                               __bf16* __restrict__ dst) {
  int i = blockIdx.x * 256 + threadIdx.x;  // float4-chunk index, total 12,582,912
  const float* s;
  int j = i;
  if (j < 2097152) s = x;
  else if ((j -= 2097152) < 4194304) s = wq;
  else if ((j -= 4194304) < 1048576) s = wk;
  else if ((j -= 1048576) < 1048576) s = wv;
  else { j -= 1048576; s = wo; }
  float4 v = ((const float4*)s)[j];
  bf16_4 o = { (__bf16)v.x, (__bf16)v.y, (__bf16)v.z, (__bf16)v.w };
  ((bf16_4*)dst)[i] = o;
}

// ---------- RoPE (in-place on bf16 Q and K) ----------
__global__ __launch_bounds__(256) void rope_k(__bf16* __restrict__ Qb, __bf16* __restrict__ Kb,
                                              const float* __restrict__ cosT,
                                              const float* __restrict__ sinT) {
  int t = blockIdx.x * 256 + threadIdx.x;
  const int NQ = S_ * (D_ / 8);
  __bf16* p;
  int row, cl8;
  if (t < NQ) { row = t >> 9; cl8 = t & 511; p = Qb + (size_t)row * D_ + cl8 * 8; }
  else        { int u = t - NQ; row = u >> 7; cl8 = u & 127; p = Kb + (size_t)row * 1024 + cl8 * 8; }
  bf16_8 v = *(bf16_8*)p;
  int fi0 = ((cl8 * 8) & 127) >> 1;
  float4 c4 = *(const float4*)&cosT[row * 64 + fi0];
  float4 s4 = *(const float4*)&sinT[row * 64 + fi0];
  float cc[4] = {c4.x, c4.y, c4.z, c4.w};
  float ss[4] = {s4.x, s4.y, s4.z, s4.w};
  bf16_8 o;
#pragma unroll
  for (int j = 0; j < 4; ++j) {
    float xr = (float)v[2 * j], xi = (float)v[2 * j + 1];
    o[2 * j]     = (__bf16)(xr * cc[j] - xi * ss[j]);
    o[2 * j + 1] = (__bf16)(xr * ss[j] + xi * cc[j]);
  }
  *(bf16_8*)p = o;
}

// ---------- fused QKV GEMM (m97-style 128x128 tile, BK=32) ----------
__global__ __launch_bounds__(256) void gemm_qkv(const __bf16* __restrict__ xb,
                                                const __bf16* __restrict__ wqb,
                                                const __bf16* __restrict__ wkb,
                                                const __bf16* __restrict__ wvb,
                                                __bf16* __restrict__ Qb,
                                                __bf16* __restrict__ Kb,
                                                __bf16* __restrict__ Vt) {
  __shared__ __bf16 As[128 * 32];
  __shared__ __bf16 Bs[128 * 32];
  const int nb = blockIdx.x, mb = blockIdx.y;
  const __bf16* W; int wrow0;
  if (nb < 32)      { W = wqb; wrow0 = nb * 128; }
  else if (nb < 40) { W = wkb; wrow0 = (nb - 32) * 128; }
  else              { W = wvb; wrow0 = (nb - 40) * 128; }
  const int tid = threadIdx.x, lane = tid & 63, wv = tid >> 6;
  const int wm = wv >> 1, wn = wv & 1;
  const int srow = lane >> 2, scol = (lane & 3) * 8;

  const __bf16* Ag0 = xb + (size_t)(mb * 128 + 2 * wv * 16 + srow) * D_ + scol;
  const __bf16* Bg0 = W  + (size_t)(wrow0 + 2 * wv * 16 + srow) * D_ + scol;
  __bf16* Al = As + 2 * wv * 512;
  __bf16* Bl = Bs + 2 * wv * 512;

  const f32x4 zv = {0.f, 0.f, 0.f, 0.f};
  f32x4 acc[4][4];
#pragma unroll
  for (int i = 0; i < 4; ++i)
#pragma unroll
    for (int j = 0; j < 4; ++j) acc[i][j] = zv;

  for (int k0 = 0; k0 < D_; k0 += 32) {
    gload_lds16(Ag0 + k0, Al);
    gload_lds16(Ag0 + (size_t)16 * D_ + k0, Al + 512);
    gload_lds16(Bg0 + k0, Bl);
    gload_lds16(Bg0 + (size_t)16 * D_ + k0, Bl + 512);
    __syncthreads();
    bf16_8 af[4], bfr[4];
#pragma unroll
    for (int i = 0; i < 4; ++i)
      af[i] = *(const bf16_8*)&As[(wm * 64 + i * 16 + (lane & 15)) * 32 + (lane >> 4) * 8];
#pragma unroll
    for (int j = 0; j < 4; ++j)
      bfr[j] = *(const bf16_8*)&Bs[(wn * 64 + j * 16 + (lane & 15)) * 32 + (lane >> 4) * 8];
#pragma unroll
    for (int i = 0; i < 4; ++i)
#pragma unroll
      for (int j = 0; j < 4; ++j)
        acc[i][j] = __builtin_amdgcn_mfma_f32_16x16x32_bf16(af[i], bfr[j], acc[i][j], 0, 0, 0);
    __syncthreads();
  }

#pragma unroll
  for (int i = 0; i < 4; ++i) {
    int row0 = mb * 128 + wm * 64 + i * 16 + (lane >> 4) * 4;
#pragma unroll
    for (int j = 0; j < 4; ++j) {
      int cl = wn * 64 + j * 16 + (lane & 15);
      if (nb < 32) {
        int colg = nb * 128 + cl;
#pragma unroll
        for (int r = 0; r < 4; ++r)
          Qb[(size_t)(row0 + r) * D_ + colg] = (__bf16)acc[i][j][r];
      } else if (nb < 40) {
        int colg = (nb - 32) * 128 + cl;
#pragma unroll
        for (int r = 0; r < 4; ++r)
          Kb[(size_t)(row0 + r) * 1024 + colg] = (__bf16)acc[i][j][r];
      } else {
        int colg = (nb - 40) * 128 + cl;
        bf16_4 pv = { (__bf16)acc[i][j][0], (__bf16)acc[i][j][1],
                      (__bf16)acc[i][j][2], (__bf16)acc[i][j][3] };
        *(bf16_4*)&Vt[(size_t)colg * S_ + row0] = pv;  // transposed store
      }
    }
  }
}

// ---------- output-projection GEMM: out(fp32) = Ob @ wo^T ----------
__global__ __launch_bounds__(256) void gemm_out(const __bf16* __restrict__ Ob,
                                                const __bf16* __restrict__ wob,
                                                float* __restrict__ Of) {
  __shared__ __bf16 As[128 * 32];
  __shared__ __bf16 Bs[128 * 32];
  const int nb = blockIdx.x, mb = blockIdx.y;
  const int tid = threadIdx.x, lane = tid & 63, wv = tid >> 6;
  const int wm = wv >> 1, wn = wv & 1;
  const int srow = lane >> 2, scol = (lane & 3) * 8;

  const __bf16* Ag0 = Ob  + (size_t)(mb * 128 + 2 * wv * 16 + srow) * D_ + scol;
  const __bf16* Bg0 = wob + (size_t)(nb * 128 + 2 * wv * 16 + srow) * D_ + scol;
  __bf16* Al = As + 2 * wv * 512;
  __bf16* Bl = Bs + 2 * wv * 512;

  const f32x4 zv = {0.f, 0.f, 0.f, 0.f};
  f32x4 acc[4][4];
#pragma unroll
  for (int i = 0; i < 4; ++i)
#pragma unroll
    for (int j = 0; j < 4; ++j) acc[i][j] = zv;

  for (int k0 = 0; k0 < D_; k0 += 32) {
    gload_lds16(Ag0 + k0, Al);
    gload_lds16(Ag0 + (size_t)16 * D_ + k0, Al + 512);
    gload_lds16(Bg0 + k0, Bl);
    gload_lds16(Bg0 + (size_t)16 * D_ + k0, Bl + 512);
    __syncthreads();
    bf16_8 af[4], bfr[4];
#pragma unroll
    for (int i = 0; i < 4; ++i)
      af[i] = *(const bf16_8*)&As[(wm * 64 + i * 16 + (lane & 15)) * 32 + (lane >> 4) * 8];
#pragma unroll
    for (int j = 0; j < 4; ++j)
      bfr[j] = *(const bf16_8*)&Bs[(wn * 64 + j * 16 + (lane & 15)) * 32 + (lane >> 4) * 8];
#pragma unroll
    for (int i = 0; i < 4; ++i)
#pragma unroll
      for (int j = 0; j < 4; ++j)
        acc[i][j] = __builtin_amdgcn_mfma_f32_16x16x32_bf16(af[i], bfr[j], acc[i][j], 0, 0, 0);
    __syncthreads();
  }

#pragma unroll
  for (int i = 0; i < 4; ++i) {
    int row0 = mb * 128 + wm * 64 + i * 16 + (lane >> 4) * 4;
#pragma unroll
    for (int j = 0; j < 4; ++j) {
      int colg = nb * 128 + wn * 64 + j * 16 + (lane & 15);
#pragma unroll
      for (int r = 0; r < 4; ++r)
        Of[(size_t)(row0 + r) * D_ + colg] = acc[i][j][r];
    }
  }
}

// ---------- flash attention (causal, GQA), paired-triangle, SWAPPED QK^T ----------
// grid: x = 16 q-tile pairs (qlo=x, qhi=31-x), y = 32 heads. 4 waves x 16 q-rows/tile.
// mfma(K,Q) -> S^T: lane holds 16 S-values for q = lane&15 (reduction lane-local).
// State per tile member: scalar m, l (for q = lane&15).
#define COMPUTE_TILE(ACC, MR, LR, AQ, QB0, DOMASK, KSB, VSB)                       \
  {                                                                                \
    f32x4 sfr_[4];                                                                 \
    __builtin_amdgcn_s_setprio(1);                                                 \
    _Pragma("unroll")                                                              \
    for (int nf = 0; nf < 4; ++nf) {                                               \
      f32x4 c_ = zv;                                                               \
      _Pragma("unroll")                                                            \
      for (int ks = 0; ks < 4; ++ks) {                                             \
        int n_ = nf * 16 + (lane & 15);                                            \
        int bo_ = (n_ * 256 + (ks * 32 + (lane >> 4) * 8) * 2) ^ ((n_ & 7) << 4);  \
        bf16_8 bk_ = *(const bf16_8*)((char*)(KSB) + bo_);                         \
        c_ = __builtin_amdgcn_mfma_f32_16x16x32_bf16(bk_, AQ[ks], c_, 0, 0, 0);    \
      }                                                                            \
      sfr_[nf] = c_;                                                               \
    }                                                                              \
    __builtin_amdgcn_s_setprio(0);                                                 \
    const int myq_ = (QB0) + w * 16 + (lane & 15);                                 \
    float pm_ = -3e38f;                                                            \
    _Pragma("unroll")                                                              \
    for (int nf = 0; nf < 4; ++nf) {                                               \
      _Pragma("unroll")                                                            \
      for (int r = 0; r < 4; ++r) {                                                \
        int kcol_ = kb * 64 + nf * 16 + (lane >> 4) * 4 + r;                       \
        float v_ = sfr_[nf][r] * sc;                                               \
        if ((DOMASK) && kcol_ > myq_) v_ = -1e9f;                                  \
        sfr_[nf][r] = v_;                                                          \
        pm_ = fmaxf(pm_, v_);                                                      \
      }                                                                            \
    }                                                                              \
    pm_ = fmaxf(pm_, __shfl_xor(pm_, 16));                                         \
    pm_ = fmaxf(pm_, __shfl_xor(pm_, 32));                                         \
    if (!__all(pm_ <= MR + 8.f)) {                                                 \
      float mn_ = fmaxf(MR, pm_);                                                  \
      float rs_ = __expf(MR - mn_);                                                \
      MR = mn_;                                                                    \
      LR *= rs_;                                                                   \
      float rsb_[4];                                                               \
      _Pragma("unroll")                                                            \
      for (int r = 0; r < 4; ++r)                                                  \
        rsb_[r] = __shfl(rs_, (lane & 48) | ((lane >> 4) * 4 + r));                \
      _Pragma("unroll")                                                            \
      for (int d = 0; d < 8; ++d)                                                  \
        _Pragma("unroll")                                                          \
        for (int r = 0; r < 4; ++r) ACC[d][r] *= rsb_[r];                          \
    }                                                                              \
    float ps_ = 0.f;                                                               \
    _Pragma("unroll")                                                              \
    for (int nf = 0; nf < 4; ++nf) {                                               \
      bf16_4 pk_;                                                                  \
      _Pragma("unroll")                                                            \
      for (int r = 0; r < 4; ++r) {                                                \
        float p_ = __expf(sfr_[nf][r] - MR);                                       \
        ps_ += p_;                                                                 \
        pk_[r] = (__bf16)p_;                                                       \
      }                                                                            \
      int bo_ = ((lane & 15) * 128 + nf * 32 + (lane >> 4) * 8) ^                  \
                (((lane & 15) & 7) << 4);                                          \
      *(bf16_4*)((char*)(&Ps[w][0]) + bo_) = pk_;                                  \
    }                                                                              \
    ps_ += __shfl_xor(ps_, 16);                                                    \
    ps_ += __shfl_xor(ps_, 32);                                                    \
    LR += ps_;                                                                     \
    bf16_8 ap_[2];                                                                 \
    _Pragma("unroll")                                                              \
    for (int ks = 0; ks < 2; ++ks) {                                               \
      int bo_ = ((lane & 15) * 128 + (ks * 32 + (lane >> 4) * 8) * 2) ^            \
                (((lane & 15) & 7) << 4);                                          \
      ap_[ks] = *(const bf16_8*)((char*)(&Ps[w][0]) + bo_);                        \
    }                                                                              \
    __builtin_amdgcn_s_setprio(1);                                                 \
    _Pragma("unroll")                                                              \
    for (int d = 0; d < 8; ++d) {                                                  \
      _Pragma("unroll")                                                            \
      for (int ks = 0; ks < 2; ++ks) {                                             \
        int dr_ = d * 16 + (lane & 15);                                            \
        int bo_ = (dr_ * 128 + (ks * 32 + (lane >> 4) * 8) * 2) ^ ((dr_ & 7) << 4);\
        bf16_8 bv_ = *(const bf16_8*)((char*)(VSB) + bo_);                         \
        ACC[d] = __builtin_amdgcn_mfma_f32_16x16x32_bf16(ap_[ks], bv_, ACC[d], 0, 0, 0); \
      }                                                                            \
    }                                                                              \
    __builtin_amdgcn_s_setprio(0);                                                 \
  }

__global__ __launch_bounds__(256) void attn_k(const __bf16* __restrict__ Qb,
                                              const __bf16* __restrict__ Kb,
                                              const __bf16* __restrict__ Vt,
                                              __bf16* __restrict__ Ob) {
  __shared__ __bf16 Ks[2][64 * 128];   // double-buffered, swizzled, row stride 256B
  __shared__ __bf16 Vs[2][128 * 64];   // Vs[d][k], row stride 128B, swizzled
  __shared__ __bf16 Ps[4][16 * 64];    // per-wave P[q][k], row stride 128B, swizzled
  const int x = blockIdx.x, h = blockIdx.y, kvh = h >> 2;
  const int qlo = x, qhi = 31 - x;
  const int tid = threadIdx.x, lane = tid & 63, w = tid >> 6;

  // Q fragments straight from global (once per block, both tiles)
  bf16_8 aq0[4], aq1[4];
#pragma unroll
  for (int ks = 0; ks < 4; ++ks) {
    int rr = w * 16 + (lane & 15);
    int cc = h * 128 + ks * 32 + (lane >> 4) * 8;
    aq0[ks] = *(const bf16_8*)&Qb[(size_t)(qlo * 64 + rr) * D_ + cc];
    aq1[ks] = *(const bf16_8*)&Qb[(size_t)(qhi * 64 + rr) * D_ + cc];
  }

  const f32x4 zv = {0.f, 0.f, 0.f, 0.f};
  f32x4 accO0[8], accO1[8];
#pragma unroll
  for (int d = 0; d < 8; ++d) { accO0[d] = zv; accO1[d] = zv; }
  float mr0 = -3e38f, lr0 = 0.f, mr1 = -3e38f, lr1 = 0.f;

  const float sc = 0.08838834764831845f;  // 1/sqrt(128)

  // staging registers (async-split: global load early, LDS-write late)
  bf16_8 rK[4], rV[4];
#define KLOAD(KB)                                                                  \
  {                                                                                \
    _Pragma("unroll")                                                              \
    for (int u = 0; u < 4; ++u) {                                                  \
      int cid = u * 256 + tid; int row = cid >> 4, c8 = cid & 15;                  \
      rK[u] = *(const bf16_8*)&Kb[(size_t)((KB) * 64 + row) * 1024 + kvh * 128 + c8 * 8]; \
    }                                                                              \
    _Pragma("unroll")                                                              \
    for (int u = 0; u < 4; ++u) {                                                  \
      int cid = u * 256 + tid; int vr = cid >> 3, c8 = cid & 7;                    \
      rV[u] = *(const bf16_8*)&Vt[(size_t)(kvh * 128 + vr) * S_ + (KB) * 64 + c8 * 8]; \
    }                                                                              \
  }
#define KSTORE(BUF)                                                                \
  {                                                                                \
    _Pragma("unroll")                                                              \
    for (int u = 0; u < 4; ++u) {                                                  \
      int cid = u * 256 + tid; int row = cid >> 4, c8 = cid & 15;                  \
      int bo = (row * 256 + c8 * 16) ^ ((row & 7) << 4);                           \
      *(bf16_8*)((char*)(&Ks[BUF][0]) + bo) = rK[u];                               \
    }                                                                              \
    _Pragma("unroll")                                                              \
    for (int u = 0; u < 4; ++u) {                                                  \
      int cid = u * 256 + tid; int vr = cid >> 3, c8 = cid & 7;                    \
      int bo = (vr * 128 + c8 * 16) ^ ((vr & 7) << 4);                             \
      *(bf16_8*)((char*)(&Vs[BUF][0]) + bo) = rV[u];                               \
    }                                                                              \
  }

  KLOAD(0);
  KSTORE(0);
  __syncthreads();

  for (int kb = 0; kb <= qhi; ++kb) {
    const int cur = kb & 1;
    if (kb < qhi) KLOAD(kb + 1);  // in flight during compute
    __bf16* ksb = &Ks[cur][0];
    __bf16* vsb = &Vs[cur][0];
    COMPUTE_TILE(accO1, mr1, lr1, aq1, qhi * 64, (kb == qhi), ksb, vsb);
    if (kb <= qlo) COMPUTE_TILE(accO0, mr0, lr0, aq0, qlo * 64, (kb == qlo), ksb, vsb);
    if (kb < qhi) {
      KSTORE(cur ^ 1);   // write NEXT tile to alt buffer (no reader conflict)
      __syncthreads();   // alt buffer ready for everyone
    }
  }

  // normalize + store both tiles (l lives at lane q = lane&15 -> shuffle per row)
  float inv0[4], inv1[4];
#pragma unroll
  for (int r = 0; r < 4; ++r) {
    int src = (lane & 48) | ((lane >> 4) * 4 + r);
    inv0[r] = 1.0f / __shfl(lr0, src);
    inv1[r] = 1.0f / __shfl(lr1, src);
  }
#pragma unroll
  for (int d = 0; d < 8; ++d) {
#pragma unroll
    for (int r = 0; r < 4; ++r) {
      size_t rl = (size_t)(qlo * 64 + w * 16 + (lane >> 4) * 4 + r);
      size_t rh = (size_t)(qhi * 64 + w * 16 + (lane >> 4) * 4 + r);
      int cc = h * 128 + d * 16 + (lane & 15);
      Ob[rl * D_ + cc] = (__bf16)(accO0[d][r] * inv0[r]);
      Ob[rh * D_ + cc] = (__bf16)(accO1[d][r] * inv1[r]);
    }
  }
}

// ---------- launch ----------
extern "C" void kernel_launch(void* const* d_in, const int* in_sizes, int n_in,
                              void* d_out, int out_size, void* d_ws, size_t ws_size,
                              hipStream_t stream) {
  const float* x    = (const float*)d_in[0];
  const float* wq   = (const float*)d_in[1];
  const float* wk   = (const float*)d_in[2];
  const float* wv   = (const float*)d_in[3];
  const float* wo   = (const float*)d_in[4];
  const float* cosT = (const float*)d_in[5];
  const float* sinT = (const float*)d_in[6];
  float* out = (float*)d_out;
  char* ws = (char*)d_ws;

  __bf16* xb  = (__bf16*)(ws + 0);            // 2048x4096; later reused as Ob
  __bf16* wqb = (__bf16*)(ws + 16777216);     // 4096x4096
  __bf16* wkb = (__bf16*)(ws + 50331648);     // 1024x4096
  __bf16* wvb = (__bf16*)(ws + 58720256);     // 1024x4096
  __bf16* wob = (__bf16*)(ws + 67108864);     // 4096x4096
  __bf16* Qb  = (__bf16*)(ws + 100663296);    // 2048x4096
  __bf16* Kb  = (__bf16*)(ws + 117440512);    // 2048x1024
  __bf16* Vt  = (__bf16*)(ws + 121634816);    // 1024x2048 (V transposed)
  __bf16* Ob  = xb;                           // alias: x consumed before attention writes

  // fused fp32 -> bf16 (dst = xb..wob contiguous)
  cvt_all<<<49152, 256, 0, stream>>>(x, wq, wk, wv, wo, xb);

  // fused QKV projection (V stored transposed)
  gemm_qkv<<<dim3(48, 16), 256, 0, stream>>>(xb, wqb, wkb, wvb, Qb, Kb, Vt);

  // RoPE on Q and K (in place)
  rope_k<<<5120, 256, 0, stream>>>(Qb, Kb, cosT, sinT);

  // causal GQA flash attention (paired triangle, swapped QK^T)
  attn_k<<<dim3(16, 32), 256, 0, stream>>>(Qb, Kb, Vt, Ob);

  // output projection -> fp32
  gemm_out<<<dim3(32, 16), 256, 0, stream>>>(Ob, wob, out);
}